// Round 3
// baseline (96.197 us; speedup 1.0000x reference)
//
#include <hip/hip_runtime.h>
#include <math.h>

// Gaussian KDE — GATHER formulation.
//
// fp32 exp(-d2/200) is exactly 0 once d2 > ~20794 (result below 2^-149),
// i.e. point-voxel distance > ~144.2. So each 13^3 voxel tile only needs
// points within 144.2 of its bounding box; everything else contributes an
// exact fp32 zero, identical to the reference's own arithmetic.
//
// One block per 13^3 tile (65 = 5*13 -> 125 blocks):
//   phase 1: bbox-cull all 2048 points, compact survivors into LDS (~110/tile)
//   phase 2: each thread sums its voxels over the LDS list (broadcast reads,
//            conflict-free), writes each voxel exactly once (no atomics, and
//            the write itself un-poisons d_out -> no memset kernel needed).

#define NXv   65
#define NYZ   (65 * 65)
#define GTOT  (65 * 65 * 65)
#define TILE  13
#define TILE3 (TILE * TILE * TILE)
#define TPB   256
#define PMAX  2048
// bbox-distance^2 cutoff: exp underflow at d2 ~= 20794; margin to 21000.
#define CUTOFF2 21000.0f

__global__ __launch_bounds__(TPB)
void kde_gather(const float* __restrict__ pc,   // (npts, 3)
                const float* __restrict__ tp,   // (3, 65, 65, 65)
                float* __restrict__ out,        // (65, 65, 65)
                int npts) {
    __shared__ float sx[PMAX], sy[PMAX], sz[PMAX];
    __shared__ float ax[NXv], ay[NXv], az[NXv];
    __shared__ int   cnt;

    const int tid = threadIdx.x;

    // tile coords: blockIdx.x = ti*25 + tj*5 + tk
    const int bt = blockIdx.x;
    const int ti = bt / 25;
    const int rm = bt - ti * 25;
    const int tj = rm / 5;
    const int tk = rm - tj * 5;
    const int i0 = ti * TILE, j0 = tj * TILE, k0 = tk * TILE;

    if (tid == 0) cnt = 0;
    // Axis coords straight from target_points so they match JAX linspace
    // bit-for-bit. tp[a][i][j][k]: x_i = tp[i*NYZ], y_j = tp[GTOT+j*65],
    // z_k = tp[2*GTOT+k].
    if (tid < NXv) {
        ax[tid] = tp[(size_t)tid * NYZ];
        ay[tid] = tp[GTOT + (size_t)tid * NXv];
        az[tid] = tp[2 * GTOT + tid];
    }
    __syncthreads();

    const float xmin = ax[i0], xmax = ax[i0 + TILE - 1];
    const float ymin = ay[j0], ymax = ay[j0 + TILE - 1];
    const float zmin = az[k0], zmax = az[k0 + TILE - 1];

    // ---- phase 1: cull + compact ----
    for (int i = tid; i < npts; i += TPB) {
        const float px = pc[3 * i + 0];
        const float py = pc[3 * i + 1];
        const float pz = pc[3 * i + 2];
        const float dx = fmaxf(fmaxf(xmin - px, px - xmax), 0.0f);
        const float dy = fmaxf(fmaxf(ymin - py, py - ymax), 0.0f);
        const float dz = fmaxf(fmaxf(zmin - pz, pz - zmax), 0.0f);
        const float d2 = dx * dx + dy * dy + dz * dz;
        if (d2 < CUTOFF2) {
            const int pos = atomicAdd(&cnt, 1);   // LDS atomic
            if (pos < PMAX) { sx[pos] = px; sy[pos] = py; sz[pos] = pz; }
        }
    }
    __syncthreads();
    const int np = cnt;

    // exp(-d2/200) == exp2(d2 * -log2(e)/200); constant folded in double.
    const float kneg     = (float)(-1.4426950408889634 / 200.0);
    const float inv_norm = 1.0f / (2.0f * 3.14159274101257324f * 100.0f);

    // ---- phase 2: 2197 voxels over 256 threads -> 9 iterations ----
    for (int t = tid; t < TILE3; t += TPB) {
        const int li = t / (TILE * TILE);
        const int r2 = t - li * (TILE * TILE);
        const int lj = r2 / TILE;
        const int lk = r2 - lj * TILE;
        const float vx = ax[i0 + li];
        const float vy = ay[j0 + lj];
        const float vz = az[k0 + lk];
        float acc = 0.0f;
        #pragma unroll 4
        for (int p = 0; p < np; ++p) {
            const float dx = vx - sx[p];   // LDS broadcast reads
            const float dy = vy - sy[p];
            const float dz = vz - sz[p];
            const float d2 = fmaf(dx, dx, fmaf(dy, dy, dz * dz));
            acc += exp2f(d2 * kneg);       // far pairs underflow to exact 0
        }
        out[(i0 + li) * NYZ + (j0 + lj) * NXv + (k0 + lk)] = acc * inv_norm;
    }
}

extern "C" void kernel_launch(void* const* d_in, const int* in_sizes, int n_in,
                              void* d_out, int out_size, void* d_ws, size_t ws_size,
                              hipStream_t stream) {
    const float* pc  = (const float*)d_in[0];   // pointcloud (N, 3)
    const float* tp  = (const float*)d_in[1];   // target_points (3, 65, 65, 65)
    float*       out = (float*)d_out;           // (65, 65, 65) fp32

    const int npts = in_sizes[0] / 3;

    // single kernel: writes every voxel exactly once (no memset needed)
    kde_gather<<<5 * 5 * 5, TPB, 0, stream>>>(pc, tp, out, npts);
}

// Round 4
// 66.328 us; speedup vs baseline: 1.4503x; 1.4503x over previous
//
#include <hip/hip_runtime.h>
#include <math.h>

// Gaussian KDE — gather over SMALL (5^3) tiles for occupancy.
//
// fp32 exp(-d2/200) is exactly 0 once d2 > ~20794 (result below 2^-149),
// i.e. point-voxel distance > ~144.2. Each 5^3 voxel tile only needs points
// within 144.2 of its bbox; all others contribute an exact fp32 zero,
// identical to the reference's own arithmetic.
//
// R3 lesson: 125 big tiles -> 1 wave/SIMD -> latency-bound (42 us, 3% occ).
// Now: 65 = 13*5 -> 13^3 = 2197 blocks of 128 threads (~17 waves/CU), ~25
// surviving points per tile, 1 phase-2 iteration per thread.

#define NXv   65
#define NYZ   (65 * 65)
#define GTOT  (65 * 65 * 65)
#define TILE  5
#define TILE3 (TILE * TILE * TILE)     // 125
#define NT    13                       // tiles per axis
#define TPB   128
#define PMAX  512                      // ~20x the mean survivors; overflow -> fallback
// bbox-distance^2 cutoff: exp underflow at d2 ~= 20794; margin to 21000.
#define CUTOFF2 21000.0f

__global__ __launch_bounds__(TPB)
void kde_gather(const float* __restrict__ pc,   // (npts, 3)
                const float* __restrict__ tp,   // (3, 65, 65, 65)
                float* __restrict__ out,        // (65, 65, 65)
                int npts) {
    __shared__ float sx[PMAX], sy[PMAX], sz[PMAX];
    __shared__ float axs[3][TILE];     // tile's axis coords
    __shared__ int   cnt;

    const int tid = threadIdx.x;

    // tile coords: blockIdx.x = ti*NT*NT + tj*NT + tk
    const int bt = blockIdx.x;
    const int ti = bt / (NT * NT);
    const int rm = bt - ti * (NT * NT);
    const int tj = rm / NT;
    const int tk = rm - tj * NT;
    const int i0 = ti * TILE, j0 = tj * TILE, k0 = tk * TILE;

    if (tid == 0) cnt = 0;
    // Axis coords straight from target_points (bit-identical to JAX linspace):
    // x_i = tp[i*NYZ], y_j = tp[GTOT + j*65], z_k = tp[2*GTOT + k].
    if (tid < 3 * TILE) {
        const int axis = tid / TILE;
        const int off  = tid - axis * TILE;
        const int idx  = ((axis == 0) ? i0 : (axis == 1) ? j0 : k0) + off;
        const int strd = (axis == 0) ? NYZ : (axis == 1) ? NXv : 1;
        axs[axis][off] = tp[(size_t)axis * GTOT + (size_t)idx * strd];
    }
    __syncthreads();

    const float xmin = axs[0][0], xmax = axs[0][TILE - 1];
    const float ymin = axs[1][0], ymax = axs[1][TILE - 1];
    const float zmin = axs[2][0], zmax = axs[2][TILE - 1];

    // ---- phase 1: cull all points against tile bbox, compact into LDS ----
    for (int i = tid; i < npts; i += TPB) {
        const float px = pc[3 * i + 0];
        const float py = pc[3 * i + 1];
        const float pz = pc[3 * i + 2];
        const float dx = fmaxf(fmaxf(xmin - px, px - xmax), 0.0f);
        const float dy = fmaxf(fmaxf(ymin - py, py - ymax), 0.0f);
        const float dz = fmaxf(fmaxf(zmin - pz, pz - zmax), 0.0f);
        const float d2 = dx * dx + dy * dy + dz * dz;
        if (d2 < CUTOFF2) {
            const int pos = atomicAdd(&cnt, 1);   // LDS atomic
            if (pos < PMAX) { sx[pos] = px; sy[pos] = py; sz[pos] = pz; }
        }
    }
    __syncthreads();
    const int np = cnt;

    // exp(-d2/200) == exp2(d2 * -log2(e)/200); constant folded in double.
    const float kneg     = (float)(-1.4426950408889634 / 200.0);
    const float inv_norm = 1.0f / (2.0f * 3.14159274101257324f * 100.0f);

    // ---- phase 2: one voxel per thread (125 of 128 active) ----
    if (tid < TILE3) {
        const int li = tid / (TILE * TILE);
        const int r2 = tid - li * (TILE * TILE);
        const int lj = r2 / TILE;
        const int lk = r2 - lj * TILE;
        const float vx = axs[0][li];
        const float vy = axs[1][lj];
        const float vz = axs[2][lk];
        float acc = 0.0f;
        if (np <= PMAX) {
            #pragma unroll 4
            for (int p = 0; p < np; ++p) {
                const float dx = vx - sx[p];   // LDS broadcast reads
                const float dy = vy - sy[p];
                const float dz = vz - sz[p];
                const float d2 = fmaf(dx, dx, fmaf(dy, dy, dz * dz));
                acc += exp2f(d2 * kneg);       // far pairs underflow to exact 0
            }
        } else {
            // overflow fallback (never expected): direct full loop, still exact
            for (int p = 0; p < npts; ++p) {
                const float dx = vx - pc[3 * p + 0];
                const float dy = vy - pc[3 * p + 1];
                const float dz = vz - pc[3 * p + 2];
                const float d2 = fmaf(dx, dx, fmaf(dy, dy, dz * dz));
                acc += exp2f(d2 * kneg);
            }
        }
        out[(i0 + li) * NYZ + (j0 + lj) * NXv + (k0 + lk)] = acc * inv_norm;
    }
}

extern "C" void kernel_launch(void* const* d_in, const int* in_sizes, int n_in,
                              void* d_out, int out_size, void* d_ws, size_t ws_size,
                              hipStream_t stream) {
    const float* pc  = (const float*)d_in[0];   // pointcloud (N, 3)
    const float* tp  = (const float*)d_in[1];   // target_points (3, 65, 65, 65)
    float*       out = (float*)d_out;           // (65, 65, 65) fp32

    const int npts = in_sizes[0] / 3;

    // single kernel: writes every voxel exactly once (no memset needed)
    kde_gather<<<NT * NT * NT, TPB, 0, stream>>>(pc, tp, out, npts);
}